// Round 1
// baseline (1613.923 us; speedup 1.0000x reference)
//
#include <hip/hip_runtime.h>
#include <math.h>

typedef unsigned short u16;
typedef unsigned int u32;
typedef __attribute__((ext_vector_type(8))) short short8;
typedef __attribute__((ext_vector_type(4))) float f32x4;

#define Bb 2
#define Tt 2048
#define Dd 2048
#define Hh 16
#define HDim 128
#define NQKV 6144

__device__ __forceinline__ u16 f2b(float f) {
    u32 u = __float_as_uint(f);
    u32 r = (u + 0x7FFFu + ((u >> 16) & 1u)) >> 16;
    return (u16)r;
}
__device__ __forceinline__ float2 b2f2(u32 u) {
    return make_float2(__uint_as_float(u << 16), __uint_as_float(u & 0xFFFF0000u));
}
__device__ __forceinline__ u32 pack2(float a, float b) {
    return (u32)f2b(a) | ((u32)f2b(b) << 16);
}

// ---------------- cast fp32 -> bf16 (vectorized) ----------------
__global__ __launch_bounds__(256) void cast_f32_bf16(const float* __restrict__ src,
                                                     u16* __restrict__ dst, int n) {
    int i = (blockIdx.x * 256 + threadIdx.x) * 4;
    if (i >= n) return;
    float4 v = *(const float4*)(src + i);
    *(uint2*)(dst + i) = make_uint2(pack2(v.x, v.y), pack2(v.z, v.w));
}

// ---------------- transpose fp32 [R][C] -> bf16 [C][R] ----------------
__global__ __launch_bounds__(256) void transpose_cast(const float* __restrict__ src,
                                                      u16* __restrict__ dst, int R, int C) {
    __shared__ float tile[32][33];
    int c0 = blockIdx.x << 5, r0 = blockIdx.y << 5;
    int tx = threadIdx.x & 31, ty = threadIdx.x >> 5;   // 32 x 8
    #pragma unroll
    for (int i = 0; i < 32; i += 8)
        tile[ty + i][tx] = src[(size_t)(r0 + ty + i) * C + c0 + tx];
    __syncthreads();
    #pragma unroll
    for (int i = 0; i < 32; i += 8)
        dst[(size_t)(c0 + ty + i) * R + r0 + tx] = f2b(tile[tx][ty + i]);
}

// ---------------- bf16 MFMA GEMM: C[M][N] = A[M][K] * Bt[N][K]^T ----------------
// 128x128 tile, BK=32, 4 waves each computing 64x64 via 4x4 grid of 16x16x32 MFMAs.
// LDS stride 40 (pad 8) -> 2-way max bank aliasing on ds_read_b128 (free per m136).
template <bool F32OUT>
__global__ __launch_bounds__(256) void gemm_bt(const u16* __restrict__ A, const u16* __restrict__ Bt,
                                               void* __restrict__ Cv, int Mn, int Nn, int Kn) {
    __shared__ __align__(16) u16 As[128 * 40];
    __shared__ __align__(16) u16 Bs[128 * 40];
    const int tid = threadIdx.x;
    const int m0 = blockIdx.y << 7, n0 = blockIdx.x << 7;
    const int wave = tid >> 6, lane = tid & 63;
    const int wm = (wave >> 1) << 6, wn = (wave & 1) << 6;
    const int l15 = lane & 15, lq = lane >> 4;

    f32x4 acc[4][4];
    #pragma unroll
    for (int i = 0; i < 4; i++)
        #pragma unroll
        for (int j = 0; j < 4; j++)
            acc[i][j] = (f32x4){0.f, 0.f, 0.f, 0.f};

    const int r1 = tid >> 2;           // staging row (0..63), +64 for second load
    const int c1 = (tid & 3) << 3;     // staging col {0,8,16,24}

    for (int k0 = 0; k0 < Kn; k0 += 32) {
        __syncthreads();
        #pragma unroll
        for (int i = 0; i < 2; i++) {
            int row = r1 + (i << 6);
            *(uint4*)&As[row * 40 + c1] = *(const uint4*)(A + (size_t)(m0 + row) * Kn + k0 + c1);
            *(uint4*)&Bs[row * 40 + c1] = *(const uint4*)(Bt + (size_t)(n0 + row) * Kn + k0 + c1);
        }
        __syncthreads();
        short8 a[4], b[4];
        #pragma unroll
        for (int i = 0; i < 4; i++) {
            a[i] = *(const short8*)&As[(wm + (i << 4) + l15) * 40 + lq * 8];
            b[i] = *(const short8*)&Bs[(wn + (i << 4) + l15) * 40 + lq * 8];
        }
        #pragma unroll
        for (int i = 0; i < 4; i++)
            #pragma unroll
            for (int j = 0; j < 4; j++)
                acc[i][j] = __builtin_amdgcn_mfma_f32_16x16x32_bf16(a[i], b[j], acc[i][j], 0, 0, 0);
    }

    // C/D layout: col = lane&15, row = (lane>>4)*4 + reg  [m89/m91 verified]
    #pragma unroll
    for (int i = 0; i < 4; i++) {
        int mbase = m0 + wm + (i << 4) + (lq << 2);
        #pragma unroll
        for (int j = 0; j < 4; j++) {
            int n = n0 + wn + (j << 4) + l15;
            #pragma unroll
            for (int r = 0; r < 4; r++) {
                if constexpr (F32OUT)
                    ((float*)Cv)[(size_t)(mbase + r) * Nn + n] = acc[i][j][r];
                else
                    ((u16*)Cv)[(size_t)(mbase + r) * Nn + n] = f2b(acc[i][j][r]);
            }
        }
    }
}

// ---------------- RoPE (interleaved) + reorder [B*T][H*384] -> 3x [B*H][T][128] ----------------
__global__ __launch_bounds__(256) void rope_reorder(const u16* __restrict__ qkv, u16* __restrict__ qh,
                                                    u16* __restrict__ kh, u16* __restrict__ vh) {
    int gid = blockIdx.x * 256 + threadIdx.x;   // (b,h,t,i): 2*16*2048*64
    int i = gid & 63;
    int t = (gid >> 6) & 2047;
    int h = (gid >> 17) & 15;
    int b = gid >> 21;
    const u16* src = qkv + ((size_t)(b * Tt + t)) * NQKV + h * 384;
    u32 uq = *(const u32*)(src + 2 * i);
    u32 uk = *(const u32*)(src + 128 + 2 * i);
    u32 uv = *(const u32*)(src + 256 + 2 * i);
    // inv_freq = 10000^(-2i/128) = 2^(-i * log2(1e4)/64)
    float ang = (float)t * exp2f(-0.20762050596f * (float)i);
    float sv, cv;
    sincosf(ang, &sv, &cv);
    float2 q = b2f2(uq), k = b2f2(uk);
    size_t o = ((size_t)(b * Hh + h) * Tt + t) * HDim + 2 * i;
    *(u32*)(qh + o) = pack2(q.x * cv - q.y * sv, q.x * sv + q.y * cv);
    *(u32*)(kh + o) = pack2(k.x * cv - k.y * sv, k.x * sv + k.y * cv);
    *(u32*)(vh + o) = uv;
}

// ---------------- flash attention (fp32 VALU, bf16 LDS tiles) ----------------
// Block: 256 threads = 16x16 grid; thread (ty,tx) owns score tile rows ty*4..+3, cols tx*4..+3
// of a 64(q) x 64(k) tile, and output d-slice tx*8..+7 for its 4 rows.
#define ATS 130   // 128 + 2 pad: k-row reads land 2-way on banks (free)

__global__ __launch_bounds__(256) void attn_kernel(const u16* __restrict__ qh, const u16* __restrict__ kh,
                                                   const u16* __restrict__ vh, u16* __restrict__ yb) {
    __shared__ __align__(16) u16 qs[64 * ATS];
    __shared__ __align__(16) u16 ks[64 * ATS];
    __shared__ __align__(16) u16 vs[64 * 128];
    const int tid = threadIdx.x;
    const int bh = blockIdx.y;
    const int q0 = blockIdx.x << 6;
    const u16* qp = qh + (size_t)bh * Tt * HDim;
    const u16* kp = kh + (size_t)bh * Tt * HDim;
    const u16* vp = vh + (size_t)bh * Tt * HDim;

    const int tx = tid & 15, ty = tid >> 4;
    const int r0 = ty << 2, c0 = tx << 2;
    const int lane = tid & 63;

    for (int idx = tid * 2; idx < 64 * 128; idx += 512) {
        int row = idx >> 7, col = idx & 127;
        *(u32*)&qs[row * ATS + col] = *(const u32*)(qp + (size_t)(q0 + row) * HDim + col);
    }

    float m_i[4], l_i[4], o_acc[4][8];
    #pragma unroll
    for (int rr = 0; rr < 4; rr++) {
        m_i[rr] = -1e30f; l_i[rr] = 0.f;
        #pragma unroll
        for (int d = 0; d < 8; d++) o_acc[rr][d] = 0.f;
    }

    const int ktiles = (q0 >> 6) + 1;
    for (int kt = 0; kt < ktiles; kt++) {
        __syncthreads();
        const int k0 = kt << 6;
        for (int idx = tid * 2; idx < 64 * 128; idx += 512) {
            int row = idx >> 7, col = idx & 127;
            *(u32*)&ks[row * ATS + col] = *(const u32*)(kp + (size_t)(k0 + row) * HDim + col);
        }
        for (int idx = tid * 4; idx < 64 * 128; idx += 1024) {
            int row = idx >> 7, col = idx & 127;
            *(uint2*)&vs[row * 128 + col] = *(const uint2*)(vp + (size_t)(k0 + row) * HDim + col);
        }
        __syncthreads();

        float s[4][4];
        #pragma unroll
        for (int rr = 0; rr < 4; rr++)
            #pragma unroll
            for (int cc = 0; cc < 4; cc++) s[rr][cc] = 0.f;

        const u16* qb = &qs[r0 * ATS];
        const u16* kb = &ks[c0 * ATS];
        for (int d = 0; d < HDim; d += 2) {
            float2 qv[4], kv[4];
            #pragma unroll
            for (int rr = 0; rr < 4; rr++) qv[rr] = b2f2(*(const u32*)(qb + rr * ATS + d));
            #pragma unroll
            for (int cc = 0; cc < 4; cc++) kv[cc] = b2f2(*(const u32*)(kb + cc * ATS + d));
            #pragma unroll
            for (int rr = 0; rr < 4; rr++)
                #pragma unroll
                for (int cc = 0; cc < 4; cc++)
                    s[rr][cc] += qv[rr].x * kv[cc].x + qv[rr].y * kv[cc].y;
        }

        const float scale = 0.08838834764831845f;  // 1/sqrt(128)
        #pragma unroll
        for (int rr = 0; rr < 4; rr++)
            #pragma unroll
            for (int cc = 0; cc < 4; cc++) s[rr][cc] *= scale;

        if (kt == ktiles - 1) {   // diagonal tile: causal mask
            #pragma unroll
            for (int rr = 0; rr < 4; rr++)
                #pragma unroll
                for (int cc = 0; cc < 4; cc++)
                    if (k0 + c0 + cc > q0 + r0 + rr) s[rr][cc] = -1e30f;
        }

        // online softmax; row-group = 16 lanes sharing ty (within one wave)
        #pragma unroll
        for (int rr = 0; rr < 4; rr++) {
            float mx = fmaxf(fmaxf(s[rr][0], s[rr][1]), fmaxf(s[rr][2], s[rr][3]));
            #pragma unroll
            for (int off = 1; off < 16; off <<= 1) mx = fmaxf(mx, __shfl_xor(mx, off, 64));
            float mnew = fmaxf(m_i[rr], mx);
            float alpha = __expf(m_i[rr] - mnew);
            m_i[rr] = mnew;
            float rsum = 0.f;
            #pragma unroll
            for (int cc = 0; cc < 4; cc++) {
                float p = __expf(s[rr][cc] - mnew);
                s[rr][cc] = p; rsum += p;
            }
            #pragma unroll
            for (int off = 1; off < 16; off <<= 1) rsum += __shfl_xor(rsum, off, 64);
            l_i[rr] = l_i[rr] * alpha + rsum;
            #pragma unroll
            for (int d = 0; d < 8; d++) o_acc[rr][d] *= alpha;
        }

        // PV: broadcast p from each tx-group member, accumulate into own d-slice
        for (int j = 0; j < 16; j++) {
            const int srcl = (lane & 48) | j;
            float pj[4][4];
            #pragma unroll
            for (int rr = 0; rr < 4; rr++)
                #pragma unroll
                for (int cc = 0; cc < 4; cc++)
                    pj[rr][cc] = __shfl(s[rr][cc], srcl, 64);
            #pragma unroll
            for (int cc = 0; cc < 4; cc++) {
                const int c = (j << 2) + cc;
                const u16* vrow = &vs[c * 128 + tx * 8];
                uint2 va = *(const uint2*)vrow;
                uint2 vb2 = *(const uint2*)(vrow + 4);
                float2 v01 = b2f2(va.x), v23 = b2f2(va.y), v45 = b2f2(vb2.x), v67 = b2f2(vb2.y);
                #pragma unroll
                for (int rr = 0; rr < 4; rr++) {
                    float p = pj[rr][cc];
                    o_acc[rr][0] += p * v01.x; o_acc[rr][1] += p * v01.y;
                    o_acc[rr][2] += p * v23.x; o_acc[rr][3] += p * v23.y;
                    o_acc[rr][4] += p * v45.x; o_acc[rr][5] += p * v45.y;
                    o_acc[rr][6] += p * v67.x; o_acc[rr][7] += p * v67.y;
                }
            }
        }
    }

    const int b = bh >> 4, h = bh & 15;
    #pragma unroll
    for (int rr = 0; rr < 4; rr++) {
        float inv = 1.0f / l_i[rr];
        int t = q0 + r0 + rr;
        u16* dst = yb + ((size_t)(b * Tt + t)) * Dd + h * HDim + tx * 8;
        uint4 o;
        o.x = pack2(o_acc[rr][0] * inv, o_acc[rr][1] * inv);
        o.y = pack2(o_acc[rr][2] * inv, o_acc[rr][3] * inv);
        o.z = pack2(o_acc[rr][4] * inv, o_acc[rr][5] * inv);
        o.w = pack2(o_acc[rr][6] * inv, o_acc[rr][7] * inv);
        *(uint4*)dst = o;
    }
}

extern "C" void kernel_launch(void* const* d_in, const int* in_sizes, int n_in,
                              void* d_out, int out_size, void* d_ws, size_t ws_size,
                              hipStream_t stream) {
    const float* x     = (const float*)d_in[0];   // [2][2048][2048]
    const float* w_qkv = (const float*)d_in[1];   // [2048][16][384]
    const float* w_out = (const float*)d_in[2];   // [2048][2048]
    float* out = (float*)d_out;                   // [2][2048][2048] fp32

    // workspace layout (bf16 elements), total 160 MB
    u16* ws    = (u16*)d_ws;
    u16* xb    = ws;                        //  8,388,608  x as bf16 [4096][2048]
    u16* wqkvT = xb + 8388608;              // 12,582,912  w_qkv^T [6144][2048]
    u16* woutT = wqkvT + 12582912;          //  4,194,304  w_out^T [2048][2048]
    u16* qkvb  = woutT + 4194304;           // 25,165,824  qkv [4096][6144]
    u16* qhb   = qkvb + 25165824;           //  8,388,608  q [32][2048][128] (rope'd)
    u16* khb   = qhb + 8388608;             //  8,388,608
    u16* vhb   = khb + 8388608;             //  8,388,608
    u16* yb    = vhb + 8388608;             //  8,388,608  attn out [4096][2048]

    cast_f32_bf16<<<8192, 256, 0, stream>>>(x, xb, 8388608);
    transpose_cast<<<dim3(192, 64), 256, 0, stream>>>(w_qkv, wqkvT, 2048, 6144);
    transpose_cast<<<dim3(64, 64), 256, 0, stream>>>(w_out, woutT, 2048, 2048);
    gemm_bt<false><<<dim3(48, 32), 256, 0, stream>>>(xb, wqkvT, (void*)qkvb, 4096, 6144, 2048);
    rope_reorder<<<16384, 256, 0, stream>>>(qkvb, qhb, khb, vhb);
    attn_kernel<<<dim3(32, 32), 256, 0, stream>>>(qhb, khb, vhb, yb);
    gemm_bt<true><<<dim3(16, 32), 256, 0, stream>>>(yb, woutT, (void*)out, 4096, 2048, 2048);
}

// Round 2
// 453.999 us; speedup vs baseline: 3.5549x; 3.5549x over previous
//
#include <hip/hip_runtime.h>
#include <math.h>

typedef unsigned short u16;
typedef unsigned int u32;
typedef __attribute__((ext_vector_type(8))) short short8;
typedef __attribute__((ext_vector_type(4))) float f32x4;

#define Bb 2
#define Tt 2048
#define Dd 2048
#define Hh 16
#define HDim 128
#define NQKV 6144

__device__ __forceinline__ u16 f2b(float f) {
    u32 u = __float_as_uint(f);
    u32 r = (u + 0x7FFFu + ((u >> 16) & 1u)) >> 16;
    return (u16)r;
}
__device__ __forceinline__ float2 b2f2(u32 u) {
    return make_float2(__uint_as_float(u << 16), __uint_as_float(u & 0xFFFF0000u));
}
__device__ __forceinline__ u32 pack2(float a, float b) {
    return (u32)f2b(a) | ((u32)f2b(b) << 16);
}

// ---------------- cast fp32 -> bf16 (vectorized) ----------------
__global__ __launch_bounds__(256) void cast_f32_bf16(const float* __restrict__ src,
                                                     u16* __restrict__ dst, int n) {
    int i = (blockIdx.x * 256 + threadIdx.x) * 4;
    if (i >= n) return;
    float4 v = *(const float4*)(src + i);
    *(uint2*)(dst + i) = make_uint2(pack2(v.x, v.y), pack2(v.z, v.w));
}

// ---------------- transpose fp32 [R][C] -> bf16 [C][R] ----------------
__global__ __launch_bounds__(256) void transpose_cast(const float* __restrict__ src,
                                                      u16* __restrict__ dst, int R, int C) {
    __shared__ float tile[32][33];
    int c0 = blockIdx.x << 5, r0 = blockIdx.y << 5;
    int tx = threadIdx.x & 31, ty = threadIdx.x >> 5;   // 32 x 8
    #pragma unroll
    for (int i = 0; i < 32; i += 8)
        tile[ty + i][tx] = src[(size_t)(r0 + ty + i) * C + c0 + tx];
    __syncthreads();
    #pragma unroll
    for (int i = 0; i < 32; i += 8)
        dst[(size_t)(c0 + ty + i) * R + r0 + tx] = f2b(tile[tx][ty + i]);
}

// ---------------- bf16 MFMA GEMM: C[M][N] = A[M][K] * Bt[N][K]^T ----------------
template <bool F32OUT>
__global__ __launch_bounds__(256) void gemm_bt(const u16* __restrict__ A, const u16* __restrict__ Bt,
                                               void* __restrict__ Cv, int Mn, int Nn, int Kn) {
    __shared__ __align__(16) u16 As[128 * 40];
    __shared__ __align__(16) u16 Bs[128 * 40];
    const int tid = threadIdx.x;
    const int m0 = blockIdx.y << 7, n0 = blockIdx.x << 7;
    const int wave = tid >> 6, lane = tid & 63;
    const int wm = (wave >> 1) << 6, wn = (wave & 1) << 6;
    const int l15 = lane & 15, lq = lane >> 4;

    f32x4 acc[4][4];
    #pragma unroll
    for (int i = 0; i < 4; i++)
        #pragma unroll
        for (int j = 0; j < 4; j++)
            acc[i][j] = (f32x4){0.f, 0.f, 0.f, 0.f};

    const int r1 = tid >> 2;
    const int c1 = (tid & 3) << 3;

    for (int k0 = 0; k0 < Kn; k0 += 32) {
        __syncthreads();
        #pragma unroll
        for (int i = 0; i < 2; i++) {
            int row = r1 + (i << 6);
            *(uint4*)&As[row * 40 + c1] = *(const uint4*)(A + (size_t)(m0 + row) * Kn + k0 + c1);
            *(uint4*)&Bs[row * 40 + c1] = *(const uint4*)(Bt + (size_t)(n0 + row) * Kn + k0 + c1);
        }
        __syncthreads();
        short8 a[4], b[4];
        #pragma unroll
        for (int i = 0; i < 4; i++) {
            a[i] = *(const short8*)&As[(wm + (i << 4) + l15) * 40 + lq * 8];
            b[i] = *(const short8*)&Bs[(wn + (i << 4) + l15) * 40 + lq * 8];
        }
        #pragma unroll
        for (int i = 0; i < 4; i++)
            #pragma unroll
            for (int j = 0; j < 4; j++)
                acc[i][j] = __builtin_amdgcn_mfma_f32_16x16x32_bf16(a[i], b[j], acc[i][j], 0, 0, 0);
    }

    #pragma unroll
    for (int i = 0; i < 4; i++) {
        int mbase = m0 + wm + (i << 4) + (lq << 2);
        #pragma unroll
        for (int j = 0; j < 4; j++) {
            int n = n0 + wn + (j << 4) + l15;
            #pragma unroll
            for (int r = 0; r < 4; r++) {
                if constexpr (F32OUT)
                    ((float*)Cv)[(size_t)(mbase + r) * Nn + n] = acc[i][j][r];
                else
                    ((u16*)Cv)[(size_t)(mbase + r) * Nn + n] = f2b(acc[i][j][r]);
            }
        }
    }
}

// ---------------- RoPE (interleaved) + reorder ----------------
__global__ __launch_bounds__(256) void rope_reorder(const u16* __restrict__ qkv, u16* __restrict__ qh,
                                                    u16* __restrict__ kh, u16* __restrict__ vh) {
    int gid = blockIdx.x * 256 + threadIdx.x;
    int i = gid & 63;
    int t = (gid >> 6) & 2047;
    int h = (gid >> 17) & 15;
    int b = gid >> 21;
    const u16* src = qkv + ((size_t)(b * Tt + t)) * NQKV + h * 384;
    u32 uq = *(const u32*)(src + 2 * i);
    u32 uk = *(const u32*)(src + 128 + 2 * i);
    u32 uv = *(const u32*)(src + 256 + 2 * i);
    float ang = (float)t * exp2f(-0.20762050596f * (float)i);
    float sv, cv;
    sincosf(ang, &sv, &cv);
    float2 q = b2f2(uq), k = b2f2(uk);
    size_t o = ((size_t)(b * Hh + h) * Tt + t) * HDim + 2 * i;
    *(u32*)(qh + o) = pack2(q.x * cv - q.y * sv, q.x * sv + q.y * cv);
    *(u32*)(kh + o) = pack2(k.x * cv - k.y * sv, k.x * sv + k.y * cv);
    *(u32*)(vh + o) = uv;
}

// ---------------- MFMA flash attention ----------------
// 512 threads = 8 waves; q-tile 128 (wave w owns q rows w*16..+15); k-tile 64.
// S^T = K·Q^T via mfma (m=k, n=q): C-layout puts q on lane&15 -> 2-step quad
// butterfly softmax; P^T -> PV A-frag via 16 shfls; V staged transposed.
// Causal balance: block handles q-tile pair (qb, 15-qb) = uniform 34 k-iters.
#define KS 136    // Ks/Qs row stride (elems); 272 B = 16B-aligned, even bank spread
#define VTS 72    // Vt row stride; 144 B

__global__ __launch_bounds__(512) void attn_mfma(const u16* __restrict__ qh, const u16* __restrict__ kh,
                                                 const u16* __restrict__ vh, u16* __restrict__ yb) {
    __shared__ __align__(16) u16 smem[17920];
    u16* Qs = smem;            // [128][136] (init only, overlaps Ks/Vt)
    u16* Ks = smem;            // [64][136]
    u16* Vt = smem + 8704;     // [128][72]  Vt[d][k]

    const int tid = threadIdx.x;
    const int bh = blockIdx.y;
    const int w = tid >> 6, lane = tid & 63;
    const int l15 = lane & 15, qa = lane >> 4;
    const u16* qp = qh + (size_t)bh * Tt * HDim;
    const u16* kp = kh + (size_t)bh * Tt * HDim;
    const u16* vp = vh + (size_t)bh * Tt * HDim;
    const int b = bh >> 4, h = bh & 15;
    const float CEXP = (float)(0.08838834764831845 * 1.4426950408889634); // scale*log2(e)

    for (int pass = 0; pass < 2; pass++) {
        const int qt = pass ? (15 - (int)blockIdx.x) : (int)blockIdx.x;
        const int qbase = qt * 128 + w * 16;

        // ---- stage Q tile, read frags ----
        __syncthreads();
        #pragma unroll
        for (int i = 0; i < 4; i++) {
            int slot = tid + (i << 9);
            int row = slot >> 4, cb = slot & 15;
            *(uint4*)&Qs[row * KS + cb * 8] =
                *(const uint4*)(qp + (size_t)(qt * 128 + row) * HDim + cb * 8);
        }
        __syncthreads();
        short8 qfrag[4];
        #pragma unroll
        for (int dc = 0; dc < 4; dc++)
            qfrag[dc] = *(const short8*)&Qs[(w * 16 + l15) * KS + dc * 32 + qa * 8];

        float m2 = -1e30f, l_i = 0.f;
        f32x4 oacc[8];
        #pragma unroll
        for (int nt = 0; nt < 8; nt++) oacc[nt] = (f32x4){0.f, 0.f, 0.f, 0.f};

        const int nkt = 2 * qt + 2;
        for (int kt = 0; kt < nkt; kt++) {
            const int k0 = kt << 6;
            __syncthreads();   // protect LDS (Q frags on first iter / prev tile)
            // stage K [64][128] -> Ks
            #pragma unroll
            for (int i = 0; i < 2; i++) {
                int slot = tid + (i << 9);
                int row = slot >> 4, cb = slot & 15;
                *(uint4*)&Ks[row * KS + cb * 8] =
                    *(const uint4*)(kp + (size_t)(k0 + row) * HDim + cb * 8);
            }
            // stage V transposed -> Vt[d][k]
            {
                int k = tid & 63;
                #pragma unroll
                for (int it = 0; it < 2; it++) {
                    int d0 = ((tid >> 6) << 3) + (it << 6);
                    uint4 vv = *(const uint4*)(vp + (size_t)(k0 + k) * HDim + d0);
                    const u16* pe = (const u16*)&vv;
                    #pragma unroll
                    for (int j = 0; j < 8; j++) Vt[(d0 + j) * VTS + k] = pe[j];
                }
            }
            __syncthreads();

            if (k0 <= qbase + 15) {   // wave-uniform causal skip
                // ---- S^T = K . Q^T ----
                float s2[4][4];
                #pragma unroll
                for (int mt = 0; mt < 4; mt++) {
                    f32x4 st = (f32x4){0.f, 0.f, 0.f, 0.f};
                    #pragma unroll
                    for (int dc = 0; dc < 4; dc++) {
                        short8 ka = *(const short8*)&Ks[(mt * 16 + l15) * KS + dc * 32 + qa * 8];
                        st = __builtin_amdgcn_mfma_f32_16x16x32_bf16(ka, qfrag[dc], st, 0, 0, 0);
                    }
                    #pragma unroll
                    for (int r = 0; r < 4; r++) s2[mt][r] = st[r] * CEXP;
                }
                // causal mask (only diagonal-straddling tiles)
                if (k0 + 63 > qbase) {
                    int qg = qbase + l15;
                    #pragma unroll
                    for (int mt = 0; mt < 4; mt++)
                        #pragma unroll
                        for (int r = 0; r < 4; r++)
                            if (k0 + mt * 16 + qa * 4 + r > qg) s2[mt][r] = -1e30f;
                }
                // ---- online softmax (exp2 domain); q = l15, reduce across quads ----
                float mx = m2;
                #pragma unroll
                for (int mt = 0; mt < 4; mt++)
                    #pragma unroll
                    for (int r = 0; r < 4; r++) mx = fmaxf(mx, s2[mt][r]);
                mx = fmaxf(mx, __shfl_xor(mx, 16, 64));
                mx = fmaxf(mx, __shfl_xor(mx, 32, 64));
                float alpha = exp2f(m2 - mx);
                m2 = mx;
                float rsum = 0.f;
                float p[4][4];
                #pragma unroll
                for (int mt = 0; mt < 4; mt++)
                    #pragma unroll
                    for (int r = 0; r < 4; r++) {
                        p[mt][r] = exp2f(s2[mt][r] - mx);
                        rsum += p[mt][r];
                    }
                rsum += __shfl_xor(rsum, 16, 64);
                rsum += __shfl_xor(rsum, 32, 64);
                l_i = l_i * alpha + rsum;
                // rescale O (O rows q = qa*4+r; alpha lives at lane q)
                float aO[4];
                #pragma unroll
                for (int r = 0; r < 4; r++) aO[r] = __shfl(alpha, qa * 4 + r, 64);
                #pragma unroll
                for (int nt = 0; nt < 8; nt++)
                    #pragma unroll
                    for (int r = 0; r < 4; r++) oacc[nt][r] *= aO[r];

                // ---- P^T -> A-frag (quad shuffles) ----
                u32 pu[4][2];
                #pragma unroll
                for (int mt = 0; mt < 4; mt++) {
                    pu[mt][0] = pack2(p[mt][0], p[mt][1]);
                    pu[mt][1] = pack2(p[mt][2], p[mt][3]);
                }
                short8 pa[2];
                const int srcA = ((qa & 1) << 5) + l15;
                const int srcB = srcA + 16;
                #pragma unroll
                for (int c = 0; c < 2; c++) {
                    u32 A0 = __shfl((int)pu[2 * c][0], srcA, 64);
                    u32 A1 = __shfl((int)pu[2 * c][1], srcA, 64);
                    u32 A2 = __shfl((int)pu[2 * c][0], srcB, 64);
                    u32 A3 = __shfl((int)pu[2 * c][1], srcB, 64);
                    u32 B0 = __shfl((int)pu[2 * c + 1][0], srcA, 64);
                    u32 B1 = __shfl((int)pu[2 * c + 1][1], srcA, 64);
                    u32 B2 = __shfl((int)pu[2 * c + 1][0], srcB, 64);
                    u32 B3 = __shfl((int)pu[2 * c + 1][1], srcB, 64);
                    u32 wv[4];
                    wv[0] = (qa & 2) ? B0 : A0;
                    wv[1] = (qa & 2) ? B1 : A1;
                    wv[2] = (qa & 2) ? B2 : A2;
                    wv[3] = (qa & 2) ? B3 : A3;
                    pa[c] = *(short8*)wv;
                }
                // ---- PV: O += P.V  (B-frag from Vt) ----
                #pragma unroll
                for (int nt = 0; nt < 8; nt++) {
                    short8 vb0 = *(const short8*)&Vt[(nt * 16 + l15) * VTS + qa * 8];
                    short8 vb1 = *(const short8*)&Vt[(nt * 16 + l15) * VTS + 32 + qa * 8];
                    oacc[nt] = __builtin_amdgcn_mfma_f32_16x16x32_bf16(pa[0], vb0, oacc[nt], 0, 0, 0);
                    oacc[nt] = __builtin_amdgcn_mfma_f32_16x16x32_bf16(pa[1], vb1, oacc[nt], 0, 0, 0);
                }
            }
        }

        // ---- epilogue: O / l, write y[b*T+t][h*128+d] ----
        float linv = 1.0f / l_i;
        float lr[4];
        #pragma unroll
        for (int r = 0; r < 4; r++) lr[r] = __shfl(linv, qa * 4 + r, 64);
        #pragma unroll
        for (int r = 0; r < 4; r++) {
            int t = qbase + qa * 4 + r;
            u16* dst = yb + ((size_t)(b * Tt + t)) * Dd + h * HDim + l15;
            #pragma unroll
            for (int nt = 0; nt < 8; nt++)
                dst[nt * 16] = f2b(oacc[nt][r] * lr[r]);
        }
    }
}

extern "C" void kernel_launch(void* const* d_in, const int* in_sizes, int n_in,
                              void* d_out, int out_size, void* d_ws, size_t ws_size,
                              hipStream_t stream) {
    const float* x     = (const float*)d_in[0];
    const float* w_qkv = (const float*)d_in[1];
    const float* w_out = (const float*)d_in[2];
    float* out = (float*)d_out;

    u16* ws    = (u16*)d_ws;
    u16* xb    = ws;
    u16* wqkvT = xb + 8388608;
    u16* woutT = wqkvT + 12582912;
    u16* qkvb  = woutT + 4194304;
    u16* qhb   = qkvb + 25165824;
    u16* khb   = qhb + 8388608;
    u16* vhb   = khb + 8388608;
    u16* yb    = vhb + 8388608;

    cast_f32_bf16<<<8192, 256, 0, stream>>>(x, xb, 8388608);
    transpose_cast<<<dim3(192, 64), 256, 0, stream>>>(w_qkv, wqkvT, 2048, 6144);
    transpose_cast<<<dim3(64, 64), 256, 0, stream>>>(w_out, woutT, 2048, 2048);
    gemm_bt<false><<<dim3(48, 32), 256, 0, stream>>>(xb, wqkvT, (void*)qkvb, 4096, 6144, 2048);
    rope_reorder<<<16384, 256, 0, stream>>>(qkvb, qhb, khb, vhb);
    attn_mfma<<<dim3(8, 32), 512, 0, stream>>>(qhb, khb, vhb, yb);
    gemm_bt<true><<<dim3(16, 32), 256, 0, stream>>>(yb, woutT, (void*)out, 4096, 2048, 2048);
}

// Round 3
// 442.802 us; speedup vs baseline: 3.6448x; 1.0253x over previous
//
#include <hip/hip_runtime.h>
#include <math.h>

typedef unsigned short u16;
typedef unsigned int u32;
typedef __attribute__((ext_vector_type(8))) short short8;
typedef __attribute__((ext_vector_type(4))) float f32x4;

#define Bb 2
#define Tt 2048
#define Dd 2048
#define Hh 16
#define HDim 128
#define NQKV 6144

__device__ __forceinline__ u16 f2b(float f) {
    u32 u = __float_as_uint(f);
    u32 r = (u + 0x7FFFu + ((u >> 16) & 1u)) >> 16;
    return (u16)r;
}
__device__ __forceinline__ float2 b2f2(u32 u) {
    return make_float2(__uint_as_float(u << 16), __uint_as_float(u & 0xFFFF0000u));
}
__device__ __forceinline__ u32 pack2(float a, float b) {
    return (u32)f2b(a) | ((u32)f2b(b) << 16);
}

// async global->LDS, 16B per lane; LDS dest = uniform base + lane*16 [m97/m104]
#define GLD16(g, l) __builtin_amdgcn_global_load_lds(                                   \
    (const __attribute__((address_space(1))) void*)(g),                                 \
    (__attribute__((address_space(3))) void*)(l), 16, 0, 0)

// ---------------- cast fp32 -> bf16 (vectorized) ----------------
__global__ __launch_bounds__(256) void cast_f32_bf16(const float* __restrict__ src,
                                                     u16* __restrict__ dst, int n) {
    int i = (blockIdx.x * 256 + threadIdx.x) * 4;
    if (i >= n) return;
    float4 v = *(const float4*)(src + i);
    *(uint2*)(dst + i) = make_uint2(pack2(v.x, v.y), pack2(v.z, v.w));
}

// ---------------- transpose fp32 [R][C] -> bf16 [C][R] ----------------
__global__ __launch_bounds__(256) void transpose_cast(const float* __restrict__ src,
                                                      u16* __restrict__ dst, int R, int C) {
    __shared__ float tile[32][33];
    int c0 = blockIdx.x << 5, r0 = blockIdx.y << 5;
    int tx = threadIdx.x & 31, ty = threadIdx.x >> 5;   // 32 x 8
    #pragma unroll
    for (int i = 0; i < 32; i += 8)
        tile[ty + i][tx] = src[(size_t)(r0 + ty + i) * C + c0 + tx];
    __syncthreads();
    #pragma unroll
    for (int i = 0; i < 32; i += 8)
        dst[(size_t)(c0 + ty + i) * R + r0 + tx] = f2b(tile[tx][ty + i]);
}

// ---------------- bf16 MFMA GEMM (m97 structure): C = A * Bt^T ----------------
// 128x128 tile, BK=32, unpadded [128][32] LDS filled via global_load_lds width=16.
// OMODE 1: fp32 flat [Mn][Nn].  OMODE 2: bf16 scatter to planar q/k/v (pre-RoPE).
template <int OMODE>
__global__ __launch_bounds__(256) void gemm_bt(const u16* __restrict__ A, const u16* __restrict__ Bt,
                                               void* __restrict__ Cv, int Mn, int Nn, int Kn) {
    __shared__ __align__(16) u16 As[128 * 32];
    __shared__ __align__(16) u16 Bs[128 * 32];
    const int tid = threadIdx.x;
    const int m0 = blockIdx.y << 7, n0 = blockIdx.x << 7;
    const int wave = tid >> 6, lane = tid & 63;
    const int wm = (wave >> 1) << 6, wn = (wave & 1) << 6;
    const int l15 = lane & 15, lq = lane >> 4;

    f32x4 acc[4][4];
    #pragma unroll
    for (int i = 0; i < 4; i++)
        #pragma unroll
        for (int j = 0; j < 4; j++)
            acc[i][j] = (f32x4){0.f, 0.f, 0.f, 0.f};

    // wave w stages rows [w*32, w*32+32): lane i -> row w*32 + i/4 (+16 on 2nd inst), col (i&3)*8
    const int srow = wave * 32 + (lane >> 2);
    const int scol = (lane & 3) << 3;
    const u16* ga = A + (size_t)(m0 + srow) * Kn + scol;
    const u16* gb = Bt + (size_t)(n0 + srow) * Kn + scol;
    u16* lA = &As[wave * 1024];
    u16* lB = &Bs[wave * 1024];

    for (int k0 = 0; k0 < Kn; k0 += 32) {
        __syncthreads();
        GLD16(ga + k0, lA);
        GLD16(ga + k0 + (size_t)16 * Kn, lA + 512);
        GLD16(gb + k0, lB);
        GLD16(gb + k0 + (size_t)16 * Kn, lB + 512);
        __syncthreads();
        short8 a[4], b[4];
        #pragma unroll
        for (int i = 0; i < 4; i++) {
            a[i] = *(const short8*)&As[(wm + (i << 4) + l15) * 32 + lq * 8];
            b[i] = *(const short8*)&Bs[(wn + (i << 4) + l15) * 32 + lq * 8];
        }
        #pragma unroll
        for (int i = 0; i < 4; i++)
            #pragma unroll
            for (int j = 0; j < 4; j++)
                acc[i][j] = __builtin_amdgcn_mfma_f32_16x16x32_bf16(a[i], b[j], acc[i][j], 0, 0, 0);
    }

    // C/D layout: col = lane&15, row = (lane>>4)*4 + reg  [m89/m91]
    #pragma unroll
    for (int i = 0; i < 4; i++) {
        int mbase = m0 + wm + (i << 4) + (lq << 2);
        #pragma unroll
        for (int j = 0; j < 4; j++) {
            int n = n0 + wn + (j << 4) + l15;
            if constexpr (OMODE == 1) {
                #pragma unroll
                for (int r = 0; r < 4; r++)
                    ((float*)Cv)[(size_t)(mbase + r) * Nn + n] = acc[i][j][r];
            } else {
                // n = h*384 + sel*128 + d  ->  planar [sel][b*16+h][t][128]
                int f = n >> 7;
                int h = f / 3, sel = f - 3 * h;
                int d = n & 127;
                u16* base = (u16*)Cv + (size_t)sel * 8388608;
                #pragma unroll
                for (int r = 0; r < 4; r++) {
                    int m = mbase + r;
                    int b = m >> 11, t = m & 2047;
                    base[(((size_t)(b * 16 + h)) * 2048 + t) * 128 + d] = f2b(acc[i][j][r]);
                }
            }
        }
    }
}

// ---------------- RoPE in place on planar q,k [64][2048][128] ----------------
__global__ __launch_bounds__(256) void rope_planar(u16* __restrict__ qk) {
    int gid = blockIdx.x * 256 + threadIdx.x;   // (z,bh,t,i): 64*2048*64
    int i = gid & 63;
    int t = (gid >> 6) & 2047;
    int bhz = gid >> 17;                        // 0..63 spans q then k
    u16* p = qk + ((size_t)bhz * 2048 + t) * 128 + 2 * i;
    float ang = (float)t * exp2f(-0.20762050596f * (float)i);
    float sv, cv;
    sincosf(ang, &sv, &cv);
    float2 xy = b2f2(*(const u32*)p);
    *(u32*)p = pack2(xy.x * cv - xy.y * sv, xy.x * sv + xy.y * cv);
}

// ---------------- MFMA flash attention ----------------
// 512 threads = 8 waves; q-tile 128 (wave w owns q rows w*16..+15); k-tile 64.
// S^T = K·Q^T via mfma (m=k, n=q): C-layout puts q on lane&15 -> 2-step quad
// butterfly softmax; P^T -> PV A-frag via 16 shfls; V staged transposed.
// Causal balance: block handles q-tile pair (qb, 15-qb) = uniform 34 k-iters.
#define KS 136    // Ks/Qs row stride (elems); 272 B = 16B-aligned, even bank spread
#define VTS 72    // Vt row stride; 144 B

__global__ __launch_bounds__(512) void attn_mfma(const u16* __restrict__ qh, const u16* __restrict__ kh,
                                                 const u16* __restrict__ vh, u16* __restrict__ yb) {
    __shared__ __align__(16) u16 smem[17920];
    u16* Qs = smem;            // [128][136] (init only, overlaps Ks/Vt)
    u16* Ks = smem;            // [64][136]
    u16* Vt = smem + 8704;     // [128][72]  Vt[d][k]

    const int tid = threadIdx.x;
    const int bh = blockIdx.y;
    const int w = tid >> 6, lane = tid & 63;
    const int l15 = lane & 15, qa = lane >> 4;
    const u16* qp = qh + (size_t)bh * Tt * HDim;
    const u16* kp = kh + (size_t)bh * Tt * HDim;
    const u16* vp = vh + (size_t)bh * Tt * HDim;
    const int b = bh >> 4, h = bh & 15;
    const float CEXP = (float)(0.08838834764831845 * 1.4426950408889634); // scale*log2(e)

    for (int pass = 0; pass < 2; pass++) {
        const int qt = pass ? (15 - (int)blockIdx.x) : (int)blockIdx.x;
        const int qbase = qt * 128 + w * 16;

        __syncthreads();
        #pragma unroll
        for (int i = 0; i < 4; i++) {
            int slot = tid + (i << 9);
            int row = slot >> 4, cb = slot & 15;
            *(uint4*)&Qs[row * KS + cb * 8] =
                *(const uint4*)(qp + (size_t)(qt * 128 + row) * HDim + cb * 8);
        }
        __syncthreads();
        short8 qfrag[4];
        #pragma unroll
        for (int dc = 0; dc < 4; dc++)
            qfrag[dc] = *(const short8*)&Qs[(w * 16 + l15) * KS + dc * 32 + qa * 8];

        float m2 = -1e30f, l_i = 0.f;
        f32x4 oacc[8];
        #pragma unroll
        for (int nt = 0; nt < 8; nt++) oacc[nt] = (f32x4){0.f, 0.f, 0.f, 0.f};

        const int nkt = 2 * qt + 2;
        for (int kt = 0; kt < nkt; kt++) {
            const int k0 = kt << 6;
            __syncthreads();
            #pragma unroll
            for (int i = 0; i < 2; i++) {
                int slot = tid + (i << 9);
                int row = slot >> 4, cb = slot & 15;
                *(uint4*)&Ks[row * KS + cb * 8] =
                    *(const uint4*)(kp + (size_t)(k0 + row) * HDim + cb * 8);
            }
            {
                int k = tid & 63;
                #pragma unroll
                for (int it = 0; it < 2; it++) {
                    int d0 = ((tid >> 6) << 3) + (it << 6);
                    uint4 vv = *(const uint4*)(vp + (size_t)(k0 + k) * HDim + d0);
                    const u16* pe = (const u16*)&vv;
                    #pragma unroll
                    for (int j = 0; j < 8; j++) Vt[(d0 + j) * VTS + k] = pe[j];
                }
            }
            __syncthreads();

            if (k0 <= qbase + 15) {
                float s2[4][4];
                #pragma unroll
                for (int mt = 0; mt < 4; mt++) {
                    f32x4 st = (f32x4){0.f, 0.f, 0.f, 0.f};
                    #pragma unroll
                    for (int dc = 0; dc < 4; dc++) {
                        short8 ka = *(const short8*)&Ks[(mt * 16 + l15) * KS + dc * 32 + qa * 8];
                        st = __builtin_amdgcn_mfma_f32_16x16x32_bf16(ka, qfrag[dc], st, 0, 0, 0);
                    }
                    #pragma unroll
                    for (int r = 0; r < 4; r++) s2[mt][r] = st[r] * CEXP;
                }
                if (k0 + 63 > qbase) {
                    int qg = qbase + l15;
                    #pragma unroll
                    for (int mt = 0; mt < 4; mt++)
                        #pragma unroll
                        for (int r = 0; r < 4; r++)
                            if (k0 + mt * 16 + qa * 4 + r > qg) s2[mt][r] = -1e30f;
                }
                float mx = m2;
                #pragma unroll
                for (int mt = 0; mt < 4; mt++)
                    #pragma unroll
                    for (int r = 0; r < 4; r++) mx = fmaxf(mx, s2[mt][r]);
                mx = fmaxf(mx, __shfl_xor(mx, 16, 64));
                mx = fmaxf(mx, __shfl_xor(mx, 32, 64));
                float alpha = exp2f(m2 - mx);
                m2 = mx;
                float rsum = 0.f;
                float p[4][4];
                #pragma unroll
                for (int mt = 0; mt < 4; mt++)
                    #pragma unroll
                    for (int r = 0; r < 4; r++) {
                        p[mt][r] = exp2f(s2[mt][r] - mx);
                        rsum += p[mt][r];
                    }
                rsum += __shfl_xor(rsum, 16, 64);
                rsum += __shfl_xor(rsum, 32, 64);
                l_i = l_i * alpha + rsum;
                float aO[4];
                #pragma unroll
                for (int r = 0; r < 4; r++) aO[r] = __shfl(alpha, qa * 4 + r, 64);
                #pragma unroll
                for (int nt = 0; nt < 8; nt++)
                    #pragma unroll
                    for (int r = 0; r < 4; r++) oacc[nt][r] *= aO[r];

                u32 pu[4][2];
                #pragma unroll
                for (int mt = 0; mt < 4; mt++) {
                    pu[mt][0] = pack2(p[mt][0], p[mt][1]);
                    pu[mt][1] = pack2(p[mt][2], p[mt][3]);
                }
                short8 pa[2];
                const int srcA = ((qa & 1) << 5) + l15;
                const int srcB = srcA + 16;
                #pragma unroll
                for (int c = 0; c < 2; c++) {
                    u32 A0 = __shfl((int)pu[2 * c][0], srcA, 64);
                    u32 A1 = __shfl((int)pu[2 * c][1], srcA, 64);
                    u32 A2 = __shfl((int)pu[2 * c][0], srcB, 64);
                    u32 A3 = __shfl((int)pu[2 * c][1], srcB, 64);
                    u32 B0 = __shfl((int)pu[2 * c + 1][0], srcA, 64);
                    u32 B1 = __shfl((int)pu[2 * c + 1][1], srcA, 64);
                    u32 B2 = __shfl((int)pu[2 * c + 1][0], srcB, 64);
                    u32 B3 = __shfl((int)pu[2 * c + 1][1], srcB, 64);
                    u32 wv[4];
                    wv[0] = (qa & 2) ? B0 : A0;
                    wv[1] = (qa & 2) ? B1 : A1;
                    wv[2] = (qa & 2) ? B2 : A2;
                    wv[3] = (qa & 2) ? B3 : A3;
                    pa[c] = *(short8*)wv;
                }
                #pragma unroll
                for (int nt = 0; nt < 8; nt++) {
                    short8 vb0 = *(const short8*)&Vt[(nt * 16 + l15) * VTS + qa * 8];
                    short8 vb1 = *(const short8*)&Vt[(nt * 16 + l15) * VTS + 32 + qa * 8];
                    oacc[nt] = __builtin_amdgcn_mfma_f32_16x16x32_bf16(pa[0], vb0, oacc[nt], 0, 0, 0);
                    oacc[nt] = __builtin_amdgcn_mfma_f32_16x16x32_bf16(pa[1], vb1, oacc[nt], 0, 0, 0);
                }
            }
        }

        float linv = 1.0f / l_i;
        float lr[4];
        #pragma unroll
        for (int r = 0; r < 4; r++) lr[r] = __shfl(linv, qa * 4 + r, 64);
        #pragma unroll
        for (int r = 0; r < 4; r++) {
            int t = qbase + qa * 4 + r;
            u16* dst = yb + ((size_t)(b * Tt + t)) * Dd + h * HDim + l15;
            #pragma unroll
            for (int nt = 0; nt < 8; nt++)
                dst[nt * 16] = f2b(oacc[nt][r] * lr[r]);
        }
    }
}

extern "C" void kernel_launch(void* const* d_in, const int* in_sizes, int n_in,
                              void* d_out, int out_size, void* d_ws, size_t ws_size,
                              hipStream_t stream) {
    const float* x     = (const float*)d_in[0];
    const float* w_qkv = (const float*)d_in[1];
    const float* w_out = (const float*)d_in[2];
    float* out = (float*)d_out;

    u16* ws    = (u16*)d_ws;
    u16* xb    = ws;                        //  8,388,608  x bf16 [4096][2048]
    u16* wqkvT = xb + 8388608;              // 12,582,912  w_qkv^T [6144][2048]
    u16* woutT = wqkvT + 12582912;          //  4,194,304  w_out^T [2048][2048]
    u16* qhb   = woutT + 4194304;           //  8,388,608  q planar [32][2048][128]
    u16* khb   = qhb + 8388608;             //  8,388,608
    u16* vhb   = khb + 8388608;             //  8,388,608
    u16* yb    = vhb + 8388608;             //  8,388,608  attn out [4096][2048]

    cast_f32_bf16<<<8192, 256, 0, stream>>>(x, xb, 8388608);
    transpose_cast<<<dim3(192, 64), 256, 0, stream>>>(w_qkv, wqkvT, 2048, 6144);
    transpose_cast<<<dim3(64, 64), 256, 0, stream>>>(w_out, woutT, 2048, 2048);
    gemm_bt<2><<<dim3(48, 32), 256, 0, stream>>>(xb, wqkvT, (void*)qhb, 4096, 6144, 2048);
    rope_planar<<<32768, 256, 0, stream>>>(qhb);
    attn_mfma<<<dim3(8, 32), 512, 0, stream>>>(qhb, khb, vhb, yb);
    gemm_bt<1><<<dim3(16, 32), 256, 0, stream>>>(yb, woutT, (void*)out, 4096, 2048, 2048);
}